// Round 1
// baseline (454.704 us; speedup 1.0000x reference)
//
#include <hip/hip_runtime.h>

typedef _Float16 f16x8 __attribute__((ext_vector_type(8)));
typedef float f32x4 __attribute__((ext_vector_type(4)));

// Monotone grid barrier counter. Zero-initialized at module load; the
// "next multiple of gridDim.x" target makes it correct across an arbitrary
// number of graph replays without any reset.
__device__ unsigned g_bar_count = 0;

struct MegaP {
    const float* sx; const int* sy; const float* qx; const int* qy;
    const float* k1; const float* bc1; const float* k2; const float* bc2;
    const float* k3; const float* bc3; const float* Wlog; const float* blog;
    const float* Wg1; const float* bg1; const float* Wg2; const float* bg2;
    const float* Wf1; const float* bf1; const float* Wf2; const float* bf2;
    float* feat1; float* feat2; float* feat3; float* mf; float* rv; float* xfpT;
    _Float16* u16; _Float16* v16; _Float16* W2h; float* out;
};

__device__ __forceinline__ void gbar() {
    __syncthreads();
    if (threadIdx.x == 0) {
        __threadfence();                               // release: wb dirty L2 (agent scope)
        unsigned nb = gridDim.x;
        unsigned my = __hip_atomic_fetch_add(&g_bar_count, 1u, __ATOMIC_ACQ_REL,
                                             __HIP_MEMORY_SCOPE_AGENT) + 1u;
        unsigned tgt = ((my + nb - 1u) / nb) * nb;     // end of this barrier's bucket
        while (__hip_atomic_load(&g_bar_count, __ATOMIC_ACQUIRE,
                                 __HIP_MEMORY_SCOPE_AGENT) < tgt)
            __builtin_amdgcn_s_sleep(2);
    }
    __syncthreads();
    __threadfence();                                   // acquire: invalidate L1/L2 for all lanes
}

// One persistent kernel, 6 phases, 5 grid barriers.
// Phase bodies identical to the previously-verified 6-kernel version,
// re-indexed as grid-stride chunk loops.
__global__ void __launch_bounds__(256, 2) mega_k(MegaP P) {
    __shared__ __align__(16) float smem[3456];   // max over phases: conv3 weights (13.8 KB)
    const int tid = threadIdx.x;
    const unsigned gsz = gridDim.x;

    // ---------------- Phase 1: conv1 (chunks 0..767) + W2h pack (chunk 768)
    for (unsigned ch = blockIdx.x; ch < 769; ch += gsz) {
        if (ch == 768) {
            for (int s = 0; s < 4; s++) {
                int slot = tid + 256*s;          // 0..1023
                int tile = slot >> 6, lane = slot & 63;
                int kt = tile >> 2, nt = tile & 3;
                int quad = lane >> 4, col = lane & 15;
                f16x8 t;
                #pragma unroll
                for (int jj = 0; jj < 8; jj++)
                    t[jj] = (_Float16)P.Wg2[(kt*32 + quad*8 + jj)*64 + nt*16 + col];
                *(f16x8*)&P.W2h[slot*8] = t;
            }
        } else {
            int n  = (int)ch >> 5;
            int oc = (int)ch & 31;
            int bi = n / 6, si = n % 6;
            const float* inp = (si < 5) ? P.sx + (size_t)((bi*5+si)*3)*4096
                                        : P.qx + (size_t)(bi*3)*4096;
            __syncthreads();                      // protect smem reuse across chunks
            if (tid < 27) smem[tid] = P.k1[oc*27 + tid];
            if (tid == 31) smem[27] = P.bc1[oc];
            __syncthreads();
            float bl = smem[27];
            for (int idx = tid; idx < 1024; idx += 256) {
                int oy = idx >> 5, ox = idx & 31;
                float acc = bl;
                #pragma unroll
                for (int ic = 0; ic < 3; ic++) {
                    const float* ip = inp + ic*4096;
                    #pragma unroll
                    for (int dy = 0; dy < 3; dy++) {
                        int iy = 2*oy + dy;
                        if (iy >= 64) continue;
                        #pragma unroll
                        for (int dx = 0; dx < 3; dx++) {
                            int ix = 2*ox + dx;
                            if (ix >= 64) continue;
                            acc += ip[iy*64+ix] * smem[ic*9 + dy*3 + dx];
                        }
                    }
                }
                P.feat1[(size_t)(n*32+oc)*1024 + idx] = fmaxf(acc, 0.f);
            }
        }
    }
    gbar();

    // ---------------- Phase 2: conv2 (288 chunks)
    for (unsigned ch = blockIdx.x; ch < 288; ch += gsz) {
        int n   = (int)ch / 12;
        int ocg = (int)ch % 12;
        __syncthreads();
        for (int e = tid; e < 1152; e += 256) smem[e] = P.k2[ocg*1152 + e];
        __syncthreads();
        int oy = tid >> 4, ox = tid & 15;
        float a0 = P.bc2[ocg*4+0], a1 = P.bc2[ocg*4+1];
        float a2 = P.bc2[ocg*4+2], a3 = P.bc2[ocg*4+3];
        const float* ib = P.feat1 + (size_t)n*32*1024;
        for (int ic = 0; ic < 32; ic++) {
            const float* ip = ib + ic*1024;
            float tap[9];
            #pragma unroll
            for (int dy = 0; dy < 3; dy++)
                #pragma unroll
                for (int dx = 0; dx < 3; dx++) {
                    int iy = 2*oy+dy, ix = 2*ox+dx;
                    tap[dy*3+dx] = (iy < 32 && ix < 32) ? ip[iy*32+ix] : 0.f;
                }
            #pragma unroll
            for (int t = 0; t < 9; t++) {
                a0 += tap[t]*smem[0*288 + ic*9 + t];
                a1 += tap[t]*smem[1*288 + ic*9 + t];
                a2 += tap[t]*smem[2*288 + ic*9 + t];
                a3 += tap[t]*smem[3*288 + ic*9 + t];
            }
        }
        size_t ob = (size_t)(n*48 + ocg*4)*256 + tid;
        P.feat2[ob        ] = fmaxf(a0, 0.f);
        P.feat2[ob + 256  ] = fmaxf(a1, 0.f);
        P.feat2[ob + 512  ] = fmaxf(a2, 0.f);
        P.feat2[ob + 768  ] = fmaxf(a3, 0.f);
    }
    gbar();

    // ---------------- Phase 3: conv3 + fused mean-pool (192 chunks)
    for (unsigned ch = blockIdx.x; ch < 192; ch += gsz) {
        int n   = (int)ch >> 3;
        int ocg = (int)ch & 7;
        __syncthreads();
        for (int e = tid; e < 3456; e += 256) smem[e] = P.k3[ocg*3456 + e];
        __syncthreads();
        int pix = tid & 63, osub = tid >> 6;
        int oy = pix >> 3, ox = pix & 7;
        int ol0 = osub*2;
        float a0 = P.bc3[ocg*8 + ol0], a1 = P.bc3[ocg*8 + ol0 + 1];
        const float* ib = P.feat2 + (size_t)n*48*256;
        for (int ic = 0; ic < 48; ic++) {
            const float* ip = ib + ic*256;
            float tap[9];
            #pragma unroll
            for (int dy = 0; dy < 3; dy++)
                #pragma unroll
                for (int dx = 0; dx < 3; dx++) {
                    int iy = 2*oy+dy, ix = 2*ox+dx;
                    tap[dy*3+dx] = (iy < 16 && ix < 16) ? ip[iy*16+ix] : 0.f;
                }
            #pragma unroll
            for (int t = 0; t < 9; t++) {
                a0 += tap[t]*smem[ ol0   *432 + ic*9 + t];
                a1 += tap[t]*smem[(ol0+1)*432 + ic*9 + t];
            }
        }
        float r0 = fmaxf(a0, 0.f), r1 = fmaxf(a1, 0.f);
        P.feat3[(size_t)(n*64 + ocg*8 + ol0  )*64 + pix] = r0;
        P.feat3[(size_t)(n*64 + ocg*8 + ol0+1)*64 + pix] = r1;
        #pragma unroll
        for (int off = 32; off >= 1; off >>= 1) {
            r0 += __shfl_xor(r0, off, 64);
            r1 += __shfl_xor(r1, off, 64);
        }
        if (pix == 0) {
            P.mf[n*64 + ocg*8 + ol0    ] = r0 * (1.f/64.f);
            P.mf[n*64 + ocg*8 + ol0 + 1] = r1 * (1.f/64.f);
        }
    }
    gbar();

    // ---------------- Phase 4: uv (192 chunks, 2 p-groups per 256-thr block) + cls (24)
    for (unsigned ch = blockIdx.x; ch < 216; ch += gsz) {
        if (ch < 192) {
            int bs = (int)ch >> 3, pp = (int)ch & 7;
            int half = tid >> 7, t = tid & 127;
            int pg = pp*2 + half;
            float (*a4)[66] = ((float(*)[66])smem) + half*4;   // [8][66] total
            __syncthreads();
            for (int e = t; e < 264; e += 128) {
                int pl = e / 66, c = e % 66;
                int p = pg*4 + pl;
                float vv;
                if (c < 64)       vv = P.feat3[(size_t)(bs*64 + c)*64 + p];
                else if (c == 64) vv = (float)(p >> 3) * 0.125f;
                else              vv = (float)(p & 7) * 0.125f;
                a4[pl][c] = vv;
            }
            __syncthreads();
            float us[4] = {0.f,0.f,0.f,0.f};
            float bg = P.bg1[t];
            float vs[4] = {bg,bg,bg,bg};
            for (int c = 0; c < 66; c++) {
                float wa = P.Wg1[c*128 + t];
                float wb = P.Wg1[(66+c)*128 + t];
                #pragma unroll
                for (int pl = 0; pl < 4; pl++) {
                    us[pl] += a4[pl][c]*wa;
                    vs[pl] += a4[pl][c]*wb;
                }
            }
            #pragma unroll
            for (int pl = 0; pl < 4; pl++) {
                int p = pg*4 + pl;
                P.u16[(size_t)(bs*64+p)*128 + t] = (_Float16)us[pl];
                P.v16[(size_t)(bs*64+p)*128 + t] = (_Float16)vs[pl];
            }
        } else {
            int n = (int)ch - 192;
            if (tid < 64) {
                float s = P.blog[tid];
                for (int c = 0; c < 64; c++) s += P.mf[n*64 + c] * P.Wlog[c*64 + tid];
                float mx = s;
                #pragma unroll
                for (int off = 32; off >= 1; off >>= 1) mx = fmaxf(mx, __shfl_xor(mx, off, 64));
                float px = __expf(s - mx);
                float se = px;
                #pragma unroll
                for (int off = 32; off >= 1; off >>= 1) se += __shfl_xor(se, off, 64);
                int bi = n/6, si = n%6;
                int lab = (si < 5) ? P.sy[bi*5+si] : P.qy[bi];
                float s_lab = __shfl(s, lab, 64);
                if (tid == 0) P.rv[n] = -(s_lab - mx - __logf(se));
            }
        }
    }
    gbar();

    // ---------------- Phase 5: relation core (576 chunks); writes xfpT transposed
    {
        int wv = tid >> 6, lane = tid & 63;
        int col = lane & 15, quad = lane >> 4;
        // W2h/bg2 invariant across chunks — hoisted
        f16x8 bf[4][4];
        #pragma unroll
        for (int kt = 0; kt < 4; kt++)
            #pragma unroll
            for (int nt = 0; nt < 4; nt++)
                bf[kt][nt] = *(const f16x8*)&P.W2h[(size_t)(((kt*4+nt)*64) + lane)*8];
        float bgv[4];
        #pragma unroll
        for (int nt = 0; nt < 4; nt++) bgv[nt] = P.bg2[nt*16 + col];
        _Float16* Vsh  = (_Float16*)smem;     // 2048 halves = 4 KB
        float*    xfred = smem + 1024;        // [4][64] floats

        for (unsigned ch = blockIdx.x; ch < 576; ch += gsz) {
            int cb = (int)ch >> 2, qc = (int)ch & 3;
            int b = cb / 36, rem = cb % 36;
            int j = rem / 6, i = rem % 6;
            const _Float16* ub = P.u16 + (size_t)(b*6 + i)*8192;
            const _Float16* vb = P.v16 + (size_t)(b*6 + j)*8192 + qc*2048;
            __syncthreads();                   // protect Vsh/xfred reuse across chunks
            *(f16x8*)&Vsh[tid*8] = *(const f16x8*)&vb[tid*8];
            f16x8 uf[4];
            {
                const _Float16* up = ub + (wv*16 + col)*128 + quad*8;
                #pragma unroll
                for (int kt = 0; kt < 4; kt++) uf[kt] = *(const f16x8*)&up[kt*32];
            }
            __syncthreads();
            float sums[4] = {0.f,0.f,0.f,0.f};
            for (int q = 0; q < 16; q++) {
                const _Float16* vp = &Vsh[q*128 + quad*8];
                f32x4 acc[4];
                #pragma unroll
                for (int nt = 0; nt < 4; nt++)
                    acc[nt] = (f32x4){bgv[nt], bgv[nt], bgv[nt], bgv[nt]};
                #pragma unroll
                for (int kt = 0; kt < 4; kt++) {
                    f16x8 vf = *(const f16x8*)&vp[kt*32];
                    f16x8 af = uf[kt] + vf;
                    af = __builtin_elementwise_max(af, (f16x8){0,0,0,0,0,0,0,0});
                    #pragma unroll
                    for (int nt = 0; nt < 4; nt++)
                        acc[nt] = __builtin_amdgcn_mfma_f32_16x16x32_f16(af, bf[kt][nt], acc[nt], 0, 0, 0);
                }
                #pragma unroll
                for (int nt = 0; nt < 4; nt++)
                    #pragma unroll
                    for (int rr = 0; rr < 4; rr++)
                        sums[nt] += fmaxf(acc[nt][rr], 0.f);
            }
            #pragma unroll
            for (int nt = 0; nt < 4; nt++) {
                sums[nt] += __shfl_xor(sums[nt], 16, 64);
                sums[nt] += __shfl_xor(sums[nt], 32, 64);
            }
            if (lane < 16) {
                #pragma unroll
                for (int nt = 0; nt < 4; nt++) xfred[wv*64 + nt*16 + lane] = sums[nt];
            }
            __syncthreads();
            // transposed layout: [n (64)][cb*4+qc (576)] → loss reads are float4-coalesced
            if (tid < 64)
                P.xfpT[(size_t)tid*576 + ch] =
                    xfred[tid] + xfred[64+tid] + xfred[128+tid] + xfred[192+tid];
        }
    }
    gbar();

    // ---------------- Phase 6: score head + losses (block 0 only; others exit)
    if (blockIdx.x == 0) {
        float* Wf1sh = smem;            // 1024
        float* wf2sh = smem + 1024;     // 16
        float* bf1sh = smem + 1040;     // 16
        float* Pmm   = smem + 1056;     // 144
        int*   lab   = (int*)(smem + 1200); // 24 ints
        float* red   = smem + 1232;     // 256
        float* ratio = smem + 1488;     // 4
        for (int e = tid; e < 1024; e += 256) Wf1sh[e] = P.Wf1[e];
        if (tid < 16) { wf2sh[tid] = P.Wf2[tid]; bf1sh[tid] = P.bf1[tid]; }
        if (tid < 24) { int bi = tid/6, si = tid%6; lab[tid] = (si < 5) ? P.sy[bi*5+si] : P.qy[bi]; }
        __syncthreads();
        if (tid < 144) {
            float hid[16];
            #pragma unroll
            for (int h = 0; h < 16; h++) hid[h] = bf1sh[h];
            for (int n = 0; n < 64; n++) {
                f32x4 vv = *(const f32x4*)&P.xfpT[(size_t)n*576 + tid*4];
                float x = vv[0] + vv[1] + vv[2] + vv[3];
                #pragma unroll
                for (int h = 0; h < 16; h++) hid[h] += x * Wf1sh[n*16 + h];
            }
            float sc = P.bf2[0];
            #pragma unroll
            for (int h = 0; h < 16; h++) sc += fmaxf(hid[h], 0.f) * wf2sh[h];
            Pmm[tid] = 1.f/(1.f + __expf(-sc));
        }
        __syncthreads();
        float e = 0.f;
        if (tid < 144) {
            int b = tid/36, r = tid%36, jj = r/6, ii = r%6;
            float y = (lab[b*6+jj] == lab[b*6+ii]) ? 1.f : 0.f;
            float d = Pmm[tid] - y;
            e = d*d;
        }
        red[tid] = e;
        __syncthreads();
        for (int s = 128; s > 0; s >>= 1) {
            if (tid < s) red[tid] += red[tid+s];
            __syncthreads();
        }
        if (tid < 4) {
            float s2 = 0.f, a2 = 0.f;
            for (int jj = 0; jj < 6; jj++)
                for (int ii = 0; ii < 6; ii++) {
                    float pa = Pmm[tid*36 + jj*6 + ii], pb = Pmm[tid*36 + ii*6 + jj];
                    float sm = 0.5f*(pa+pb), an = 0.5f*(pa-pb);
                    s2 += sm*sm; a2 += an*an;
                }
            float sn = sqrtf(s2), anq = sqrtf(a2);
            ratio[tid] = (sn - anq)/(sn + anq);
        }
        __syncthreads();
        if (tid == 0) {
            float sl = 0.25f*(ratio[0]+ratio[1]+ratio[2]+ratio[3]);
            float euc = red[0] * (1.f/144.f);
            float cs = 0.f;
            for (int k = 0; k < 24; k++) cs += P.rv[k];
            P.out[0] = cs * (1.f/24.f);
            P.out[1] = euc - 0.1f*sl;
            P.out[2] = sl;
        }
    }
}

extern "C" void kernel_launch(void* const* d_in, const int* in_sizes, int n_in,
                              void* d_out, int out_size, void* d_ws, size_t ws_size,
                              hipStream_t stream) {
    float* ws    = (float*)d_ws;
    float* feat1 = ws;                    // 786432
    float* feat2 = feat1 + 786432;        // 294912
    float* feat3 = feat2 + 294912;        // 98304
    float* mf    = feat3 + 98304;         // 1536
    float* rv    = mf    + 1536;          // 32 (24 used)
    float* xfpT  = rv    + 32;            // 64*576 = 36864
    _Float16* u16 = (_Float16*)(xfpT + 36864);  // 196608 halves
    _Float16* v16 = u16 + 196608;               // 196608 halves
    _Float16* W2h = v16 + 196608;               // 8192 halves

    MegaP P;
    P.sx = (const float*)d_in[0];  P.sy  = (const int*)d_in[1];
    P.qx = (const float*)d_in[2];  P.qy  = (const int*)d_in[3];
    P.k1 = (const float*)d_in[4];  P.bc1 = (const float*)d_in[5];
    P.k2 = (const float*)d_in[6];  P.bc2 = (const float*)d_in[7];
    P.k3 = (const float*)d_in[8];  P.bc3 = (const float*)d_in[9];
    P.Wlog = (const float*)d_in[10]; P.blog = (const float*)d_in[11];
    P.Wg1  = (const float*)d_in[12]; P.bg1  = (const float*)d_in[13];
    P.Wg2  = (const float*)d_in[14]; P.bg2  = (const float*)d_in[15];
    P.Wf1  = (const float*)d_in[16]; P.bf1  = (const float*)d_in[17];
    P.Wf2  = (const float*)d_in[18]; P.bf2  = (const float*)d_in[19];
    P.feat1 = feat1; P.feat2 = feat2; P.feat3 = feat3; P.mf = mf; P.rv = rv;
    P.xfpT = xfpT; P.u16 = u16; P.v16 = v16; P.W2h = W2h; P.out = (float*)d_out;

    // Grid clamped to guaranteed co-residency (manual barrier requirement).
    static int grid = 0;
    if (grid == 0) {
        int nb = 0;
        if (hipOccupancyMaxActiveBlocksPerMultiprocessor(&nb, mega_k, 256, 0) != hipSuccess || nb < 1)
            nb = 1;
        int dev = 0;
        hipGetDevice(&dev);
        hipDeviceProp_t prop;
        int ncu = (hipGetDeviceProperties(&prop, dev) == hipSuccess) ? prop.multiProcessorCount : 0;
        if (ncu < 1) ncu = 64;
        long g = (long)nb * (long)ncu;
        grid = (int)(g < 576 ? g : 576);
    }
    hipLaunchKernelGGL(mega_k, dim3(grid), dim3(256), 0, stream, P);
}

// Round 2
// 291.474 us; speedup vs baseline: 1.5600x; 1.5600x over previous
//
#include <hip/hip_runtime.h>

typedef _Float16 f16x8 __attribute__((ext_vector_type(8)));
typedef float f32x4 __attribute__((ext_vector_type(4)));

// Monotone grid barrier counter. Zero-initialized at module load; the
// "next multiple of gridDim.x" target makes it correct across an arbitrary
// number of graph replays without any reset.
__device__ unsigned g_bar_count = 0;

struct MegaP {
    const float* sx; const int* sy; const float* qx; const int* qy;
    const float* k1; const float* bc1; const float* k2; const float* bc2;
    const float* k3; const float* bc3; const float* Wlog; const float* blog;
    const float* Wg1; const float* bg1; const float* Wg2; const float* bg2;
    const float* Wf1; const float* bf1; const float* Wf2; const float* bf2;
    float* feat1; float* feat2; float* feat3; float* mf; float* rv; float* xfpT;
    _Float16* u16; _Float16* v16; _Float16* W2h; float* out;
};

// Grid barrier, cheap form:
//  - arrive: ONE atomic RMW per block, RELEASE at agent scope
//    (emits the single buffer_wbl2 needed for cross-XCD visibility).
//  - spin: RELAXED loads only — NO cache-op per poll (the round-1 version
//    used ACQUIRE polls; each emitted buffer_inv sc1, thrashing L1/L2
//    chip-wide and costing ~230 us per barrier).
//  - depart: one ACQUIRE load on thread 0 (single buffer_inv for this CU's
//    L1 + XCD L2), then __syncthreads() orders the whole block behind it.
__device__ __forceinline__ void gbar() {
    __syncthreads();
    if (threadIdx.x == 0) {
        unsigned nb = gridDim.x;
        unsigned my = __hip_atomic_fetch_add(&g_bar_count, 1u, __ATOMIC_RELEASE,
                                             __HIP_MEMORY_SCOPE_AGENT) + 1u;
        unsigned tgt = ((my + nb - 1u) / nb) * nb;     // end of this barrier's bucket
        while (__hip_atomic_load(&g_bar_count, __ATOMIC_RELAXED,
                                 __HIP_MEMORY_SCOPE_AGENT) < tgt)
            __builtin_amdgcn_s_sleep(8);
        (void)__hip_atomic_load(&g_bar_count, __ATOMIC_ACQUIRE,
                                __HIP_MEMORY_SCOPE_AGENT);   // inv L1/L2 once
    }
    __syncthreads();
}

// One persistent kernel, 6 phases, 5 grid barriers.
// Phase bodies identical to the verified 6-kernel version (absmax 0.0),
// re-indexed as grid-stride chunk loops.
__global__ void __launch_bounds__(256, 2) mega_k(MegaP P) {
    __shared__ __align__(16) float smem[3456];   // max over phases: conv3 weights (13.8 KB)
    const int tid = threadIdx.x;
    const unsigned gsz = gridDim.x;

    // ---------------- Phase 1: conv1 (chunks 0..767) + W2h pack (chunk 768)
    for (unsigned ch = blockIdx.x; ch < 769; ch += gsz) {
        if (ch == 768) {
            for (int s = 0; s < 4; s++) {
                int slot = tid + 256*s;          // 0..1023
                int tile = slot >> 6, lane = slot & 63;
                int kt = tile >> 2, nt = tile & 3;
                int quad = lane >> 4, col = lane & 15;
                f16x8 t;
                #pragma unroll
                for (int jj = 0; jj < 8; jj++)
                    t[jj] = (_Float16)P.Wg2[(kt*32 + quad*8 + jj)*64 + nt*16 + col];
                *(f16x8*)&P.W2h[slot*8] = t;
            }
        } else {
            int n  = (int)ch >> 5;
            int oc = (int)ch & 31;
            int bi = n / 6, si = n % 6;
            const float* inp = (si < 5) ? P.sx + (size_t)((bi*5+si)*3)*4096
                                        : P.qx + (size_t)(bi*3)*4096;
            __syncthreads();                      // protect smem reuse across chunks
            if (tid < 27) smem[tid] = P.k1[oc*27 + tid];
            if (tid == 31) smem[27] = P.bc1[oc];
            __syncthreads();
            float bl = smem[27];
            for (int idx = tid; idx < 1024; idx += 256) {
                int oy = idx >> 5, ox = idx & 31;
                float acc = bl;
                #pragma unroll
                for (int ic = 0; ic < 3; ic++) {
                    const float* ip = inp + ic*4096;
                    #pragma unroll
                    for (int dy = 0; dy < 3; dy++) {
                        int iy = 2*oy + dy;
                        if (iy >= 64) continue;
                        #pragma unroll
                        for (int dx = 0; dx < 3; dx++) {
                            int ix = 2*ox + dx;
                            if (ix >= 64) continue;
                            acc += ip[iy*64+ix] * smem[ic*9 + dy*3 + dx];
                        }
                    }
                }
                P.feat1[(size_t)(n*32+oc)*1024 + idx] = fmaxf(acc, 0.f);
            }
        }
    }
    gbar();

    // ---------------- Phase 2: conv2 (288 chunks)
    for (unsigned ch = blockIdx.x; ch < 288; ch += gsz) {
        int n   = (int)ch / 12;
        int ocg = (int)ch % 12;
        __syncthreads();
        for (int e = tid; e < 1152; e += 256) smem[e] = P.k2[ocg*1152 + e];
        __syncthreads();
        int oy = tid >> 4, ox = tid & 15;
        float a0 = P.bc2[ocg*4+0], a1 = P.bc2[ocg*4+1];
        float a2 = P.bc2[ocg*4+2], a3 = P.bc2[ocg*4+3];
        const float* ib = P.feat1 + (size_t)n*32*1024;
        for (int ic = 0; ic < 32; ic++) {
            const float* ip = ib + ic*1024;
            float tap[9];
            #pragma unroll
            for (int dy = 0; dy < 3; dy++)
                #pragma unroll
                for (int dx = 0; dx < 3; dx++) {
                    int iy = 2*oy+dy, ix = 2*ox+dx;
                    tap[dy*3+dx] = (iy < 32 && ix < 32) ? ip[iy*32+ix] : 0.f;
                }
            #pragma unroll
            for (int t = 0; t < 9; t++) {
                a0 += tap[t]*smem[0*288 + ic*9 + t];
                a1 += tap[t]*smem[1*288 + ic*9 + t];
                a2 += tap[t]*smem[2*288 + ic*9 + t];
                a3 += tap[t]*smem[3*288 + ic*9 + t];
            }
        }
        size_t ob = (size_t)(n*48 + ocg*4)*256 + tid;
        P.feat2[ob        ] = fmaxf(a0, 0.f);
        P.feat2[ob + 256  ] = fmaxf(a1, 0.f);
        P.feat2[ob + 512  ] = fmaxf(a2, 0.f);
        P.feat2[ob + 768  ] = fmaxf(a3, 0.f);
    }
    gbar();

    // ---------------- Phase 3: conv3 + fused mean-pool (192 chunks)
    for (unsigned ch = blockIdx.x; ch < 192; ch += gsz) {
        int n   = (int)ch >> 3;
        int ocg = (int)ch & 7;
        __syncthreads();
        for (int e = tid; e < 3456; e += 256) smem[e] = P.k3[ocg*3456 + e];
        __syncthreads();
        int pix = tid & 63, osub = tid >> 6;
        int oy = pix >> 3, ox = pix & 7;
        int ol0 = osub*2;
        float a0 = P.bc3[ocg*8 + ol0], a1 = P.bc3[ocg*8 + ol0 + 1];
        const float* ib = P.feat2 + (size_t)n*48*256;
        for (int ic = 0; ic < 48; ic++) {
            const float* ip = ib + ic*256;
            float tap[9];
            #pragma unroll
            for (int dy = 0; dy < 3; dy++)
                #pragma unroll
                for (int dx = 0; dx < 3; dx++) {
                    int iy = 2*oy+dy, ix = 2*ox+dx;
                    tap[dy*3+dx] = (iy < 16 && ix < 16) ? ip[iy*16+ix] : 0.f;
                }
            #pragma unroll
            for (int t = 0; t < 9; t++) {
                a0 += tap[t]*smem[ ol0   *432 + ic*9 + t];
                a1 += tap[t]*smem[(ol0+1)*432 + ic*9 + t];
            }
        }
        float r0 = fmaxf(a0, 0.f), r1 = fmaxf(a1, 0.f);
        P.feat3[(size_t)(n*64 + ocg*8 + ol0  )*64 + pix] = r0;
        P.feat3[(size_t)(n*64 + ocg*8 + ol0+1)*64 + pix] = r1;
        #pragma unroll
        for (int off = 32; off >= 1; off >>= 1) {
            r0 += __shfl_xor(r0, off, 64);
            r1 += __shfl_xor(r1, off, 64);
        }
        if (pix == 0) {
            P.mf[n*64 + ocg*8 + ol0    ] = r0 * (1.f/64.f);
            P.mf[n*64 + ocg*8 + ol0 + 1] = r1 * (1.f/64.f);
        }
    }
    gbar();

    // ---------------- Phase 4: uv (192 chunks, 2 p-groups per 256-thr block) + cls (24)
    for (unsigned ch = blockIdx.x; ch < 216; ch += gsz) {
        if (ch < 192) {
            int bs = (int)ch >> 3, pp = (int)ch & 7;
            int half = tid >> 7, t = tid & 127;
            int pg = pp*2 + half;
            float (*a4)[66] = ((float(*)[66])smem) + half*4;   // [8][66] total
            __syncthreads();
            for (int e = t; e < 264; e += 128) {
                int pl = e / 66, c = e % 66;
                int p = pg*4 + pl;
                float vv;
                if (c < 64)       vv = P.feat3[(size_t)(bs*64 + c)*64 + p];
                else if (c == 64) vv = (float)(p >> 3) * 0.125f;
                else              vv = (float)(p & 7) * 0.125f;
                a4[pl][c] = vv;
            }
            __syncthreads();
            float us[4] = {0.f,0.f,0.f,0.f};
            float bg = P.bg1[t];
            float vs[4] = {bg,bg,bg,bg};
            for (int c = 0; c < 66; c++) {
                float wa = P.Wg1[c*128 + t];
                float wb = P.Wg1[(66+c)*128 + t];
                #pragma unroll
                for (int pl = 0; pl < 4; pl++) {
                    us[pl] += a4[pl][c]*wa;
                    vs[pl] += a4[pl][c]*wb;
                }
            }
            #pragma unroll
            for (int pl = 0; pl < 4; pl++) {
                int p = pg*4 + pl;
                P.u16[(size_t)(bs*64+p)*128 + t] = (_Float16)us[pl];
                P.v16[(size_t)(bs*64+p)*128 + t] = (_Float16)vs[pl];
            }
        } else {
            int n = (int)ch - 192;
            if (tid < 64) {
                float s = P.blog[tid];
                for (int c = 0; c < 64; c++) s += P.mf[n*64 + c] * P.Wlog[c*64 + tid];
                float mx = s;
                #pragma unroll
                for (int off = 32; off >= 1; off >>= 1) mx = fmaxf(mx, __shfl_xor(mx, off, 64));
                float px = __expf(s - mx);
                float se = px;
                #pragma unroll
                for (int off = 32; off >= 1; off >>= 1) se += __shfl_xor(se, off, 64);
                int bi = n/6, si = n%6;
                int lab = (si < 5) ? P.sy[bi*5+si] : P.qy[bi];
                float s_lab = __shfl(s, lab, 64);
                if (tid == 0) P.rv[n] = -(s_lab - mx - __logf(se));
            }
        }
    }
    gbar();

    // ---------------- Phase 5: relation core (576 chunks); writes xfpT transposed
    {
        int wv = tid >> 6, lane = tid & 63;
        int col = lane & 15, quad = lane >> 4;
        // W2h/bg2 invariant across chunks — hoisted
        f16x8 bf[4][4];
        #pragma unroll
        for (int kt = 0; kt < 4; kt++)
            #pragma unroll
            for (int nt = 0; nt < 4; nt++)
                bf[kt][nt] = *(const f16x8*)&P.W2h[(size_t)(((kt*4+nt)*64) + lane)*8];
        float bgv[4];
        #pragma unroll
        for (int nt = 0; nt < 4; nt++) bgv[nt] = P.bg2[nt*16 + col];
        _Float16* Vsh  = (_Float16*)smem;     // 2048 halves = 4 KB
        float*    xfred = smem + 1024;        // [4][64] floats

        for (unsigned ch = blockIdx.x; ch < 576; ch += gsz) {
            int cb = (int)ch >> 2, qc = (int)ch & 3;
            int b = cb / 36, rem = cb % 36;
            int j = rem / 6, i = rem % 6;
            const _Float16* ub = P.u16 + (size_t)(b*6 + i)*8192;
            const _Float16* vb = P.v16 + (size_t)(b*6 + j)*8192 + qc*2048;
            __syncthreads();                   // protect Vsh/xfred reuse across chunks
            *(f16x8*)&Vsh[tid*8] = *(const f16x8*)&vb[tid*8];
            f16x8 uf[4];
            {
                const _Float16* up = ub + (wv*16 + col)*128 + quad*8;
                #pragma unroll
                for (int kt = 0; kt < 4; kt++) uf[kt] = *(const f16x8*)&up[kt*32];
            }
            __syncthreads();
            float sums[4] = {0.f,0.f,0.f,0.f};
            for (int q = 0; q < 16; q++) {
                const _Float16* vp = &Vsh[q*128 + quad*8];
                f32x4 acc[4];
                #pragma unroll
                for (int nt = 0; nt < 4; nt++)
                    acc[nt] = (f32x4){bgv[nt], bgv[nt], bgv[nt], bgv[nt]};
                #pragma unroll
                for (int kt = 0; kt < 4; kt++) {
                    f16x8 vf = *(const f16x8*)&vp[kt*32];
                    f16x8 af = uf[kt] + vf;
                    af = __builtin_elementwise_max(af, (f16x8){0,0,0,0,0,0,0,0});
                    #pragma unroll
                    for (int nt = 0; nt < 4; nt++)
                        acc[nt] = __builtin_amdgcn_mfma_f32_16x16x32_f16(af, bf[kt][nt], acc[nt], 0, 0, 0);
                }
                #pragma unroll
                for (int nt = 0; nt < 4; nt++)
                    #pragma unroll
                    for (int rr = 0; rr < 4; rr++)
                        sums[nt] += fmaxf(acc[nt][rr], 0.f);
            }
            #pragma unroll
            for (int nt = 0; nt < 4; nt++) {
                sums[nt] += __shfl_xor(sums[nt], 16, 64);
                sums[nt] += __shfl_xor(sums[nt], 32, 64);
            }
            if (lane < 16) {
                #pragma unroll
                for (int nt = 0; nt < 4; nt++) xfred[wv*64 + nt*16 + lane] = sums[nt];
            }
            __syncthreads();
            // transposed layout: [n (64)][cb*4+qc (576)] → loss reads are float4-coalesced
            if (tid < 64)
                P.xfpT[(size_t)tid*576 + ch] =
                    xfred[tid] + xfred[64+tid] + xfred[128+tid] + xfred[192+tid];
        }
    }
    gbar();

    // ---------------- Phase 6: score head + losses (block 0 only; others exit)
    if (blockIdx.x == 0) {
        float* Wf1sh = smem;            // 1024
        float* wf2sh = smem + 1024;     // 16
        float* bf1sh = smem + 1040;     // 16
        float* Pmm   = smem + 1056;     // 144
        int*   lab   = (int*)(smem + 1200); // 24 ints
        float* red   = smem + 1232;     // 256
        float* ratio = smem + 1488;     // 4
        for (int e = tid; e < 1024; e += 256) Wf1sh[e] = P.Wf1[e];
        if (tid < 16) { wf2sh[tid] = P.Wf2[tid]; bf1sh[tid] = P.bf1[tid]; }
        if (tid < 24) { int bi = tid/6, si = tid%6; lab[tid] = (si < 5) ? P.sy[bi*5+si] : P.qy[bi]; }
        __syncthreads();
        if (tid < 144) {
            float hid[16];
            #pragma unroll
            for (int h = 0; h < 16; h++) hid[h] = bf1sh[h];
            for (int n = 0; n < 64; n++) {
                f32x4 vv = *(const f32x4*)&P.xfpT[(size_t)n*576 + tid*4];
                float x = vv[0] + vv[1] + vv[2] + vv[3];
                #pragma unroll
                for (int h = 0; h < 16; h++) hid[h] += x * Wf1sh[n*16 + h];
            }
            float sc = P.bf2[0];
            #pragma unroll
            for (int h = 0; h < 16; h++) sc += fmaxf(hid[h], 0.f) * wf2sh[h];
            Pmm[tid] = 1.f/(1.f + __expf(-sc));
        }
        __syncthreads();
        float e = 0.f;
        if (tid < 144) {
            int b = tid/36, r = tid%36, jj = r/6, ii = r%6;
            float y = (lab[b*6+jj] == lab[b*6+ii]) ? 1.f : 0.f;
            float d = Pmm[tid] - y;
            e = d*d;
        }
        red[tid] = e;
        __syncthreads();
        for (int s = 128; s > 0; s >>= 1) {
            if (tid < s) red[tid] += red[tid+s];
            __syncthreads();
        }
        if (tid < 4) {
            float s2 = 0.f, a2 = 0.f;
            for (int jj = 0; jj < 6; jj++)
                for (int ii = 0; ii < 6; ii++) {
                    float pa = Pmm[tid*36 + jj*6 + ii], pb = Pmm[tid*36 + ii*6 + jj];
                    float sm = 0.5f*(pa+pb), an = 0.5f*(pa-pb);
                    s2 += sm*sm; a2 += an*an;
                }
            float sn = sqrtf(s2), anq = sqrtf(a2);
            ratio[tid] = (sn - anq)/(sn + anq);
        }
        __syncthreads();
        if (tid == 0) {
            float sl = 0.25f*(ratio[0]+ratio[1]+ratio[2]+ratio[3]);
            float euc = red[0] * (1.f/144.f);
            float cs = 0.f;
            for (int k = 0; k < 24; k++) cs += P.rv[k];
            P.out[0] = cs * (1.f/24.f);
            P.out[1] = euc - 0.1f*sl;
            P.out[2] = sl;
        }
    }
}

extern "C" void kernel_launch(void* const* d_in, const int* in_sizes, int n_in,
                              void* d_out, int out_size, void* d_ws, size_t ws_size,
                              hipStream_t stream) {
    float* ws    = (float*)d_ws;
    float* feat1 = ws;                    // 786432
    float* feat2 = feat1 + 786432;        // 294912
    float* feat3 = feat2 + 294912;        // 98304
    float* mf    = feat3 + 98304;         // 1536
    float* rv    = mf    + 1536;          // 32 (24 used)
    float* xfpT  = rv    + 32;            // 64*576 = 36864
    _Float16* u16 = (_Float16*)(xfpT + 36864);  // 196608 halves
    _Float16* v16 = u16 + 196608;               // 196608 halves
    _Float16* W2h = v16 + 196608;               // 8192 halves

    MegaP P;
    P.sx = (const float*)d_in[0];  P.sy  = (const int*)d_in[1];
    P.qx = (const float*)d_in[2];  P.qy  = (const int*)d_in[3];
    P.k1 = (const float*)d_in[4];  P.bc1 = (const float*)d_in[5];
    P.k2 = (const float*)d_in[6];  P.bc2 = (const float*)d_in[7];
    P.k3 = (const float*)d_in[8];  P.bc3 = (const float*)d_in[9];
    P.Wlog = (const float*)d_in[10]; P.blog = (const float*)d_in[11];
    P.Wg1  = (const float*)d_in[12]; P.bg1  = (const float*)d_in[13];
    P.Wg2  = (const float*)d_in[14]; P.bg2  = (const float*)d_in[15];
    P.Wf1  = (const float*)d_in[16]; P.bf1  = (const float*)d_in[17];
    P.Wf2  = (const float*)d_in[18]; P.bf2  = (const float*)d_in[19];
    P.feat1 = feat1; P.feat2 = feat2; P.feat3 = feat3; P.mf = mf; P.rv = rv;
    P.xfpT = xfpT; P.u16 = u16; P.v16 = v16; P.W2h = W2h; P.out = (float*)d_out;

    // Grid clamped to guaranteed co-residency (manual barrier requirement).
    static int grid = 0;
    if (grid == 0) {
        int nb = 0;
        if (hipOccupancyMaxActiveBlocksPerMultiprocessor(&nb, mega_k, 256, 0) != hipSuccess || nb < 1)
            nb = 1;
        int dev = 0;
        hipGetDevice(&dev);
        hipDeviceProp_t prop;
        int ncu = (hipGetDeviceProperties(&prop, dev) == hipSuccess) ? prop.multiProcessorCount : 0;
        if (ncu < 1) ncu = 64;
        long g = (long)nb * (long)ncu;
        grid = (int)(g < 576 ? g : 576);
    }
    hipLaunchKernelGGL(mega_k, dim3(grid), dim3(256), 0, stream, P);
}

// Round 3
// 178.541 us; speedup vs baseline: 2.5468x; 1.6325x over previous
//
#include <hip/hip_runtime.h>

typedef _Float16 f16x8 __attribute__((ext_vector_type(8)));
typedef float f32x4 __attribute__((ext_vector_type(4)));

// XCD-affinity note: workgroup→XCD assignment round-robins by blockIdx
// (idx % 8 on MI355X, 8 XCDs). All kernels below SWIZZLE their block
// decode so every block touching image n has blockIdx ≡ n (mod 8):
// producers and consumers of feat*[n] share one XCD's L2, killing the
// 8× cross-XCD re-fetch amplification measured in rounds 1-2
// (FETCH_SIZE 24 MB vs ~10 MB working set). Pure perf heuristic —
// correctness does not depend on the mapping.

// ---------------- conv1: (24,3,64,64) -> (24,32,32,32), stride2 SAME, relu
// block 768 additionally packs Wg2 into f16 MFMA B-fragment order.
__global__ void conv1_k(const float* __restrict__ sx, const float* __restrict__ qx,
                        const float* __restrict__ w, const float* __restrict__ bias,
                        float* __restrict__ out,
                        const float* __restrict__ Wg2, _Float16* __restrict__ W2h) {
    if (blockIdx.x == 768) {
        for (int s = 0; s < 4; s++) {
            int slot = threadIdx.x + 256*s;      // 0..1023
            int tile = slot >> 6, lane = slot & 63;
            int kt = tile >> 2, nt = tile & 3;
            int quad = lane >> 4, col = lane & 15;
            f16x8 t;
            #pragma unroll
            for (int jj = 0; jj < 8; jj++)
                t[jj] = (_Float16)Wg2[(kt*32 + quad*8 + jj)*64 + nt*16 + col];
            *(f16x8*)&W2h[slot*8] = t;
        }
        return;
    }
    // swizzled decode: n ≡ blockIdx (mod 8)
    int r8 = blockIdx.x & 7, q = blockIdx.x >> 3;   // q 0..95
    int n  = (q >> 5)*8 + r8;    // 0..23
    int oc = q & 31;             // 0..31
    int bi = n / 6, si = n % 6;
    const float* inp = (si < 5) ? sx + (size_t)((bi*5+si)*3)*4096
                                : qx + (size_t)(bi*3)*4096;
    __shared__ float wl[27];
    __shared__ float bl;
    if (threadIdx.x < 27) wl[threadIdx.x] = w[oc*27 + threadIdx.x];
    if (threadIdx.x == 0) bl = bias[oc];
    __syncthreads();
    for (int idx = threadIdx.x; idx < 1024; idx += 256) {
        int oy = idx >> 5, ox = idx & 31;
        float acc = bl;
        #pragma unroll
        for (int ic = 0; ic < 3; ic++) {
            const float* ip = inp + ic*4096;
            #pragma unroll
            for (int dy = 0; dy < 3; dy++) {
                int iy = 2*oy + dy;
                if (iy >= 64) continue;
                #pragma unroll
                for (int dx = 0; dx < 3; dx++) {
                    int ix = 2*ox + dx;
                    if (ix >= 64) continue;
                    acc += ip[iy*64+ix] * wl[ic*9 + dy*3 + dx];
                }
            }
        }
        out[(size_t)(n*32+oc)*1024 + idx] = fmaxf(acc, 0.f);
    }
}

// ---------------- conv2: (24,32,32,32) -> (24,48,16,16), oc-group=4
// LDS triple-buffered input-plane staging, prefetch distance 2:
// the 32-iteration serial ic loop was L2/L3-latency-bound (one miss
// exposed per iteration). Same FMA order → bitwise-identical results.
__global__ void conv2_k(const float* __restrict__ in, const float* __restrict__ w,
                        const float* __restrict__ bias, float* __restrict__ out) {
    int r8 = blockIdx.x & 7, q = blockIdx.x >> 3;   // q 0..35
    int n   = (q / 12)*8 + r8;   // 0..23
    int ocg = q % 12;
    __shared__ float wl[1152];
    __shared__ float pin[3][33*32];    // padded stride 33
    const int tid = threadIdx.x;
    for (int e = tid; e < 1152; e += 256) wl[e] = w[ocg*1152 + e];
    const float* ib = in + (size_t)n*32*1024;
    int srow = (tid*4) >> 5, scol = (tid*4) & 31;
    {   // stage plane 0
        f32x4 t0 = *(const f32x4*)&ib[tid*4];
        float* d = &pin[0][srow*33 + scol];
        d[0]=t0[0]; d[1]=t0[1]; d[2]=t0[2]; d[3]=t0[3];
    }
    f32x4 t1 = *(const f32x4*)&ib[1024 + tid*4];   // plane 1 in flight
    __syncthreads();
    int oy = tid >> 4, ox = tid & 15;
    float a0 = bias[ocg*4+0], a1 = bias[ocg*4+1];
    float a2 = bias[ocg*4+2], a3 = bias[ocg*4+3];
    for (int ic = 0; ic < 32; ic++) {
        f32x4 t2 = t1;
        if (ic + 2 < 32) t2 = *(const f32x4*)&ib[(size_t)(ic+2)*1024 + tid*4];
        const float* pp = pin[ic % 3];
        float tap[9];
        #pragma unroll
        for (int dy = 0; dy < 3; dy++)
            #pragma unroll
            for (int dx = 0; dx < 3; dx++) {
                int iy = 2*oy+dy, ix = 2*ox+dx;
                tap[dy*3+dx] = (iy < 32 && ix < 32) ? pp[iy*33 + ix] : 0.f;
            }
        #pragma unroll
        for (int t = 0; t < 9; t++) {
            a0 += tap[t]*wl[0*288 + ic*9 + t];
            a1 += tap[t]*wl[1*288 + ic*9 + t];
            a2 += tap[t]*wl[2*288 + ic*9 + t];
            a3 += tap[t]*wl[3*288 + ic*9 + t];
        }
        if (ic + 1 < 32) {
            float* d = &pin[(ic+1) % 3][srow*33 + scol];
            d[0]=t1[0]; d[1]=t1[1]; d[2]=t1[2]; d[3]=t1[3];
        }
        t1 = t2;
        __syncthreads();
    }
    size_t ob = (size_t)(n*48 + ocg*4)*256 + tid;
    out[ob        ] = fmaxf(a0, 0.f);
    out[ob + 256  ] = fmaxf(a1, 0.f);
    out[ob + 512  ] = fmaxf(a2, 0.f);
    out[ob + 768  ] = fmaxf(a3, 0.f);
}

// ---------------- conv3 + fused mean-pool: (24,48,16,16) -> (24,64,8,8) + mf(24,64)
// same staging scheme (1 float/thread per plane, stride-17 pad).
__global__ void conv3_k(const float* __restrict__ in, const float* __restrict__ w,
                        const float* __restrict__ bias, float* __restrict__ out,
                        float* __restrict__ mf) {
    int r8 = blockIdx.x & 7, q = blockIdx.x >> 3;   // q 0..23
    int n   = (q >> 3)*8 + r8;   // 0..23
    int ocg = q & 7;
    __shared__ float wl[3456];
    __shared__ float pin[3][17*16];
    const int tid = threadIdx.x;
    for (int e = tid; e < 3456; e += 256) wl[e] = w[ocg*3456 + e];
    const float* ib = in + (size_t)n*48*256;
    int srow = tid >> 4, scol = tid & 15;
    pin[0][srow*17 + scol] = ib[tid];
    float t1 = ib[256 + tid];
    __syncthreads();
    int pix = tid & 63, osub = tid >> 6;
    int oy = pix >> 3, ox = pix & 7;
    int ol0 = osub*2;
    float a0 = bias[ocg*8 + ol0], a1 = bias[ocg*8 + ol0 + 1];
    for (int ic = 0; ic < 48; ic++) {
        float t2 = t1;
        if (ic + 2 < 48) t2 = ib[(size_t)(ic+2)*256 + tid];
        const float* pp = pin[ic % 3];
        float tap[9];
        #pragma unroll
        for (int dy = 0; dy < 3; dy++)
            #pragma unroll
            for (int dx = 0; dx < 3; dx++) {
                int iy = 2*oy+dy, ix = 2*ox+dx;
                tap[dy*3+dx] = (iy < 16 && ix < 16) ? pp[iy*17 + ix] : 0.f;
            }
        #pragma unroll
        for (int t = 0; t < 9; t++) {
            a0 += tap[t]*wl[ ol0   *432 + ic*9 + t];
            a1 += tap[t]*wl[(ol0+1)*432 + ic*9 + t];
        }
        if (ic + 1 < 48) pin[(ic+1) % 3][srow*17 + scol] = t1;
        t1 = t2;
        __syncthreads();
    }
    float r0 = fmaxf(a0, 0.f), r1 = fmaxf(a1, 0.f);
    out[(size_t)(n*64 + ocg*8 + ol0  )*64 + pix] = r0;
    out[(size_t)(n*64 + ocg*8 + ol0+1)*64 + pix] = r1;
    #pragma unroll
    for (int off = 32; off >= 1; off >>= 1) {
        r0 += __shfl_xor(r0, off, 64);
        r1 += __shfl_xor(r1, off, 64);
    }
    if (pix == 0) {
        mf[n*64 + ocg*8 + ol0    ] = r0 * (1.f/64.f);
        mf[n*64 + ocg*8 + ol0 + 1] = r1 * (1.f/64.f);
    }
}

// ---------------- uv (blocks 0..383, f16 out, swizzled) + cls head (384..407)
__global__ void uvcls_k(const float* __restrict__ feat3, const float* __restrict__ Wg1,
                        const float* __restrict__ bg1, _Float16* __restrict__ u,
                        _Float16* __restrict__ v,
                        const float* __restrict__ mf, const int* __restrict__ sy,
                        const int* __restrict__ qy, const float* __restrict__ Wlog,
                        const float* __restrict__ blog, float* __restrict__ rv) {
    int tid = threadIdx.x;   // 128
    if (blockIdx.x >= 384) {
        int n = blockIdx.x - 384;
        if (tid >= 64) return;
        int lane = tid;
        float s = blog[lane];
        for (int c = 0; c < 64; c++) s += mf[n*64 + c] * Wlog[c*64 + lane];
        float mx = s;
        #pragma unroll
        for (int off = 32; off >= 1; off >>= 1) mx = fmaxf(mx, __shfl_xor(mx, off, 64));
        float p = __expf(s - mx);
        float se = p;
        #pragma unroll
        for (int off = 32; off >= 1; off >>= 1) se += __shfl_xor(se, off, 64);
        int bi = n/6, si = n%6;
        int lab = (si < 5) ? sy[bi*5+si] : qy[bi];
        float s_lab = __shfl(s, lab, 64);
        if (lane == 0) rv[n] = -(s_lab - mx - __logf(se));
        return;
    }
    int r8 = blockIdx.x & 7, q = blockIdx.x >> 3;  // q 0..47
    int bs = (q >> 4)*8 + r8;    // 0..23
    int pg = q & 15;             // p-group of 4
    __shared__ float a4[4][66];
    for (int e = tid; e < 264; e += 128) {
        int pl = e / 66, c = e % 66;
        int p = pg*4 + pl;
        float vv;
        if (c < 64)       vv = feat3[(size_t)(bs*64 + c)*64 + p];
        else if (c == 64) vv = (float)(p >> 3) * 0.125f;
        else              vv = (float)(p & 7) * 0.125f;
        a4[pl][c] = vv;
    }
    __syncthreads();
    float us[4] = {0.f,0.f,0.f,0.f};
    float bg = bg1[tid];
    float vs[4] = {bg,bg,bg,bg};
    for (int c = 0; c < 66; c++) {
        float wa = Wg1[c*128 + tid];
        float wb = Wg1[(66+c)*128 + tid];
        #pragma unroll
        for (int pl = 0; pl < 4; pl++) {
            us[pl] += a4[pl][c]*wa;
            vs[pl] += a4[pl][c]*wb;
        }
    }
    #pragma unroll
    for (int pl = 0; pl < 4; pl++) {
        int p = pg*4 + pl;
        u[(size_t)(bs*64+p)*128 + tid] = (_Float16)us[pl];
        v[(size_t)(bs*64+p)*128 + tid] = (_Float16)vs[pl];
    }
}

// ---------------- relation core, q-split x4; batch b pinned to XCD pair {2b,2b+1}
__global__ void __launch_bounds__(256) rel_k(
        const _Float16* __restrict__ U, const _Float16* __restrict__ V,
        const _Float16* __restrict__ W2h, const float* __restrict__ bg2,
        float* __restrict__ xfpart) {
    __shared__ __align__(16) _Float16 Vsh[16*128];
    __shared__ float xfred[4][64];

    // swizzled decode: logical within-batch index m = 0..143
    int r8 = blockIdx.x & 7, qq = blockIdx.x >> 3;   // qq 0..71
    int b = r8 >> 1;
    int m = (qq << 1) | (r8 & 1);    // 0..143
    int cb = m >> 2, qc = m & 3;     // cb = j*6+i
    int j = cb / 6, i = cb % 6;
    int tid  = threadIdx.x;
    int wv   = tid >> 6, lane = tid & 63;
    int col  = lane & 15, quad = lane >> 4;

    const _Float16* ub = U + (size_t)(b*6 + i)*8192;
    const _Float16* vb = V + (size_t)(b*6 + j)*8192 + qc*16*128;

    *(f16x8*)&Vsh[tid*8] = *(const f16x8*)&vb[tid*8];

    f16x8 uf[4];
    {
        const _Float16* up = ub + (wv*16 + col)*128 + quad*8;
        #pragma unroll
        for (int kt = 0; kt < 4; kt++) uf[kt] = *(const f16x8*)&up[kt*32];
    }
    f16x8 bf[4][4];
    #pragma unroll
    for (int kt = 0; kt < 4; kt++)
        #pragma unroll
        for (int nt = 0; nt < 4; nt++)
            bf[kt][nt] = *(const f16x8*)&W2h[(size_t)(((kt*4+nt)*64) + lane)*8];
    float bgv[4];
    #pragma unroll
    for (int nt = 0; nt < 4; nt++) bgv[nt] = bg2[nt*16 + col];

    __syncthreads();

    float sums[4] = {0.f,0.f,0.f,0.f};
    for (int q = 0; q < 16; q++) {
        const _Float16* vp = &Vsh[q*128 + quad*8];
        f32x4 acc[4];
        #pragma unroll
        for (int nt = 0; nt < 4; nt++)
            acc[nt] = (f32x4){bgv[nt], bgv[nt], bgv[nt], bgv[nt]};
        #pragma unroll
        for (int kt = 0; kt < 4; kt++) {
            f16x8 vf = *(const f16x8*)&vp[kt*32];
            f16x8 af = uf[kt] + vf;
            af = __builtin_elementwise_max(af, (f16x8){0,0,0,0,0,0,0,0});
            #pragma unroll
            for (int nt = 0; nt < 4; nt++)
                acc[nt] = __builtin_amdgcn_mfma_f32_16x16x32_f16(af, bf[kt][nt], acc[nt], 0, 0, 0);
        }
        #pragma unroll
        for (int nt = 0; nt < 4; nt++)
            #pragma unroll
            for (int rr = 0; rr < 4; rr++)
                sums[nt] += fmaxf(acc[nt][rr], 0.f);
    }

    #pragma unroll
    for (int nt = 0; nt < 4; nt++) {
        sums[nt] += __shfl_xor(sums[nt], 16, 64);
        sums[nt] += __shfl_xor(sums[nt], 32, 64);
    }
    if (lane < 16) {
        #pragma unroll
        for (int nt = 0; nt < 4; nt++) xfred[wv][nt*16 + lane] = sums[nt];
    }
    __syncthreads();
    if (tid < 64)
        xfpart[(size_t)(b*144 + m)*64 + tid] =
            xfred[0][tid] + xfred[1][tid] + xfred[2][tid] + xfred[3][tid];
}

// ---------------- score head + all losses
__global__ void loss_k(const float* __restrict__ xfp, const float* __restrict__ rv,
                       const int* __restrict__ sy, const int* __restrict__ qy,
                       const float* __restrict__ Wf1, const float* __restrict__ bf1,
                       const float* __restrict__ Wf2, const float* __restrict__ bf2,
                       float* __restrict__ out) {
    __shared__ float Wf1sh[1024];
    __shared__ float wf2sh[16];
    __shared__ float bf1sh[16];
    __shared__ float Pm[144];
    __shared__ int lab[24];
    __shared__ float red[256];
    __shared__ float ratio[4];
    int tid = threadIdx.x;
    for (int e = tid; e < 1024; e += 256) Wf1sh[e] = Wf1[e];
    if (tid < 16) { wf2sh[tid] = Wf2[tid]; bf1sh[tid] = bf1[tid]; }
    if (tid < 24) { int bi = tid/6, si = tid%6; lab[tid] = (si < 5) ? sy[bi*5+si] : qy[bi]; }
    __syncthreads();
    if (tid < 144) {
        float hid[16];
        #pragma unroll
        for (int h = 0; h < 16; h++) hid[h] = bf1sh[h];
        const float* xb = xfp + (size_t)tid*4*64;
        for (int n = 0; n < 64; n++) {
            float x = xb[n] + xb[64+n] + xb[128+n] + xb[192+n];
            #pragma unroll
            for (int h = 0; h < 16; h++) hid[h] += x * Wf1sh[n*16 + h];
        }
        float sc = bf2[0];
        #pragma unroll
        for (int h = 0; h < 16; h++) sc += fmaxf(hid[h], 0.f) * wf2sh[h];
        Pm[tid] = 1.f/(1.f + __expf(-sc));
    }
    __syncthreads();
    float e = 0.f;
    if (tid < 144) {
        int b = tid/36, r = tid%36, jj = r/6, ii = r%6;
        float y = (lab[b*6+jj] == lab[b*6+ii]) ? 1.f : 0.f;
        float d = Pm[tid] - y;
        e = d*d;
    }
    red[tid] = e;
    __syncthreads();
    for (int s = 128; s > 0; s >>= 1) {
        if (tid < s) red[tid] += red[tid+s];
        __syncthreads();
    }
    if (tid < 4) {
        float s2 = 0.f, a2 = 0.f;
        for (int jj = 0; jj < 6; jj++)
            for (int ii = 0; ii < 6; ii++) {
                float pa = Pm[tid*36 + jj*6 + ii], pb = Pm[tid*36 + ii*6 + jj];
                float sm = 0.5f*(pa+pb), an = 0.5f*(pa-pb);
                s2 += sm*sm; a2 += an*an;
            }
        float sn = sqrtf(s2), anq = sqrtf(a2);
        ratio[tid] = (sn - anq)/(sn + anq);
    }
    __syncthreads();
    if (tid == 0) {
        float sl = 0.25f*(ratio[0]+ratio[1]+ratio[2]+ratio[3]);
        float euc = red[0] * (1.f/144.f);
        float cs = 0.f;
        for (int k = 0; k < 24; k++) cs += rv[k];
        out[0] = cs * (1.f/24.f);
        out[1] = euc - 0.1f*sl;
        out[2] = sl;
    }
}

extern "C" void kernel_launch(void* const* d_in, const int* in_sizes, int n_in,
                              void* d_out, int out_size, void* d_ws, size_t ws_size,
                              hipStream_t stream) {
    const float* sx   = (const float*)d_in[0];
    const int*   sy   = (const int*)  d_in[1];
    const float* qx   = (const float*)d_in[2];
    const int*   qy   = (const int*)  d_in[3];
    const float* k1   = (const float*)d_in[4];
    const float* bc1  = (const float*)d_in[5];
    const float* k2   = (const float*)d_in[6];
    const float* bc2  = (const float*)d_in[7];
    const float* k3   = (const float*)d_in[8];
    const float* bc3  = (const float*)d_in[9];
    const float* Wlog = (const float*)d_in[10];
    const float* blog = (const float*)d_in[11];
    const float* Wg1  = (const float*)d_in[12];
    const float* bg1  = (const float*)d_in[13];
    const float* Wg2  = (const float*)d_in[14];
    const float* bg2  = (const float*)d_in[15];
    const float* Wf1  = (const float*)d_in[16];
    const float* bf1  = (const float*)d_in[17];
    const float* Wf2  = (const float*)d_in[18];
    const float* bf2  = (const float*)d_in[19];

    float* ws    = (float*)d_ws;
    float* feat1 = ws;                    // 786432
    float* feat2 = feat1 + 786432;        // 294912
    float* feat3 = feat2 + 294912;        // 98304
    float* mf    = feat3 + 98304;         // 1536
    float* rv    = mf    + 1536;          // 32 (24 used)
    float* xfp   = rv    + 32;            // 576*64 = 36864
    _Float16* u16 = (_Float16*)(xfp + 36864);  // 196608 halves
    _Float16* v16 = u16 + 196608;              // 196608 halves
    _Float16* W2h = v16 + 196608;              // 8192 halves
    float* out   = (float*)d_out;

    conv1_k <<<769,    256, 0, stream>>>(sx, qx, k1, bc1, feat1, Wg2, W2h);
    conv2_k <<<24*12,  256, 0, stream>>>(feat1, k2, bc2, feat2);
    conv3_k <<<24*8,   256, 0, stream>>>(feat2, k3, bc3, feat3, mf);
    uvcls_k <<<408,    128, 0, stream>>>(feat3, Wg1, bg1, u16, v16,
                                         mf, sy, qy, Wlog, blog, rv);
    rel_k   <<<576,    256, 0, stream>>>(u16, v16, W2h, bg2, xfp);
    loss_k  <<<1,      256, 0, stream>>>(xfp, rv, sy, qy, Wf1, bf1, Wf2, bf2, out);
}